// Round 6
// baseline (203.399 us; speedup 1.0000x reference)
//
#include <hip/hip_runtime.h>
#include <hip/hip_bf16.h>

// B=2, S=2048, D=1024, H=16, dk=64. INPUTS FP32, OUTPUT FP32. M = 4096 rows.
// ROUND 24 (= r23 + compile fix). PIPELINED GEMM K-LOOP. r22 counters:
// MfmaUtil 15%, 9.6M LDS bank conflicts (16-way on 128-B-stride ds_read),
// full stage latency exposed per K-step by [stage; vmcnt(0); barrier] convoy.
//   - BK=32, double-buffered LDS (2x16KB, fits under the 34.8KB epilogue Ct)
//   - stage(k+1) issued at top of step k; s_waitcnt vmcnt(4) waits ONLY tile
//     k's loads (tile k+1 stays in flight across the barrier); raw s_barrier
//     (no __syncthreads vmcnt(0) drain). ds_reads are consumed by MFMAs
//     before BAR2 (compiler lgkm waits) so no DS write/read race.
//   - FRAGMENT-MAJOR LDS: per-chunk lane-contiguous 16B fragments -> ds_reads
//     are lane-linear b128 with imm offsets, ZERO bank conflicts. Staging
//     writes this layout via per-lane pre-permuted global source addresses.
// Also: x+Wqkv conversions merged into one dispatch.

typedef __bf16 bf16x8 __attribute__((ext_vector_type(8)));
typedef float f32x4 __attribute__((ext_vector_type(4)));

#define LOG2E 1.4426950408889634f

__device__ __forceinline__ ushort f2bf(float f) {
  __hip_bfloat16 h = __float2bfloat16(f);
  return __builtin_bit_cast(ushort, h);
}

__device__ __forceinline__ uint pack2(float a, float b) {
  return (uint)f2bf(a) | ((uint)f2bf(b) << 16);
}

// truncating bf16x2 pack in one v_perm_b32
__device__ __forceinline__ uint pack2t(float a, float b) {
  return __builtin_amdgcn_perm(__builtin_bit_cast(uint, b),
                               __builtin_bit_cast(uint, a), 0x07060302u);
}

// single-instruction 2^x (quarter-rate trans pipe)
__device__ __forceinline__ float fexp2(float x) {
#if __has_builtin(__builtin_amdgcn_exp2f)
  return __builtin_amdgcn_exp2f(x);
#else
  float r;
  asm volatile("v_exp_f32 %0, %1\n\ts_nop 0" : "=v"(r) : "v"(x));
  return r;
#endif
}

#define CBAR() __asm__ __volatile__("" ::: "memory")

__device__ __forceinline__ void gl2lds16(const ushort* g, ushort* l) {
  __builtin_amdgcn_global_load_lds(
      (const __attribute__((address_space(1))) void*)g,
      (__attribute__((address_space(3))) void*)l, 16, 0, 0);
}

// ------------------------------------------------------- fp32 -> bf16 convs
__global__ __launch_bounds__(256) void conv_bf16(const float* __restrict__ src,
                                                 ushort* __restrict__ dst,
                                                 int n8) {
  int i = blockIdx.x * 256 + threadIdx.x;
  if (i >= n8) return;
  const float4* s = (const float4*)src + (long)i * 2;
  float4 a = s[0], b = s[1];
  uint4 pk = {pack2(a.x, a.y), pack2(a.z, a.w), pack2(b.x, b.y), pack2(b.z, b.w)};
  ((uint4*)dst)[i] = pk;
}

// two-segment conversion (x -> xh, Wqkv -> wqkvh) in one dispatch
__global__ __launch_bounds__(256) void conv_bf16_2(
    const float* __restrict__ s0, ushort* __restrict__ d0, int n0,
    const float* __restrict__ s1, ushort* __restrict__ d1, int n1) {
  int i = blockIdx.x * 256 + threadIdx.x;
  const float* src;
  ushort* dst;
  if (i < n0) {
    src = s0; dst = d0;
  } else {
    i -= n0;
    if (i >= n1) return;
    src = s1; dst = d1;
  }
  const float4* s = (const float4*)src + (long)i * 2;
  float4 a = s[0], b = s[1];
  uint4 pk = {pack2(a.x, a.y), pack2(a.z, a.w), pack2(b.x, b.y), pack2(b.z, b.w)};
  ((uint4*)dst)[i] = pk;
}

// ---------------------------------------------------------------- GEMM (NT)
// A [M x 1024] bf16 row-major, B [N x 1024] bf16 row-major (B^T GEMM).
// epi==0: QKV epilogue via LDS staging + coalesced uint4 stores (validated r22).
// epi==1: plain fp32 C row store.
__global__ __launch_bounds__(256) void gemm_bt(
    const ushort* __restrict__ A, const ushort* __restrict__ B, int nbn,
    ushort* __restrict__ qb, ushort* __restrict__ kb, ushort* __restrict__ vb,
    float* __restrict__ Cout, int epi) {
  __shared__ __align__(16) ushort SMEM[17408];  // 2 x (A 4096 | B 4096) dbuf, or Ct
  const int tid = threadIdx.x;
  const int w = tid >> 6, lane = tid & 63, quad = lane >> 4, lc = lane & 15;
  const int bid = blockIdx.x;
  const int bm = bid / nbn, bn = bid % nbn;
  const int wm = (w & 1) * 64, wn = (w >> 1) * 64;

  f32x4 acc[4][4] = {};

  const ushort* Ag = A + (long)bm * 131072;
  const ushort* Bg = B + (long)bn * 131072;

  // fragment-major staging: chunk c (0..7) of a 128x32 tile holds rows
  // (c>>2)*64 + (c&3)*16 + (lane&15), cols (lane>>4)*8 .. +7, lane-contiguous.
  // wave w stages chunks {w, w+4} of A and of B (4 gl2lds16 per thread/stage).
  const int rowc0 = w * 16 + (lane & 15);
  const int colb = (lane >> 4) * 8;
  const int aoff0 = rowc0 * 1024 + colb;          // chunk w   (rows 0..63)
  const int aoff1 = aoff0 + 65536;                // chunk w+4 (rows 64..127)

  ushort* b0 = SMEM;
  ushort* b1 = SMEM + 8192;

#define STAGE(BUF, K0)                                                         \
  {                                                                            \
    gl2lds16(Ag + aoff0 + (K0), (BUF) + w * 512);                              \
    gl2lds16(Ag + aoff1 + (K0), (BUF) + (w + 4) * 512);                        \
    gl2lds16(Bg + aoff0 + (K0), (BUF) + 4096 + w * 512);                       \
    gl2lds16(Bg + aoff1 + (K0), (BUF) + 4096 + (w + 4) * 512);                 \
  }

  STAGE(b0, 0);
  for (int k = 0; k < 32; ++k) {
    ushort* cur = (k & 1) ? b1 : b0;
    ushort* nxt = (k & 1) ? b0 : b1;
    if (k < 31) {
      STAGE(nxt, (k + 1) * 32);
      asm volatile("s_waitcnt vmcnt(4)" ::: "memory");  // tile k landed
    } else {
      asm volatile("s_waitcnt vmcnt(0)" ::: "memory");
    }
    CBAR();
    __builtin_amdgcn_s_barrier();
    CBAR();
    {
      const ushort* Ab = cur + (w & 1) * 2048 + lane * 8;
      const ushort* Bb = cur + 4096 + (w >> 1) * 2048 + lane * 8;
      bf16x8 af[4], bfr[4];
      for (int t = 0; t < 4; ++t) af[t] = *(const bf16x8*)&Ab[t * 512];
      for (int t = 0; t < 4; ++t) bfr[t] = *(const bf16x8*)&Bb[t * 512];
      for (int rt = 0; rt < 4; ++rt)
        for (int ct = 0; ct < 4; ++ct)
          acc[rt][ct] = __builtin_amdgcn_mfma_f32_16x16x32_bf16(
              af[rt], bfr[ct], acc[rt][ct], 0, 0, 0);
    }
    CBAR();
    __builtin_amdgcn_s_barrier();  // all waves done reading cur before restage
    CBAR();
  }
#undef STAGE

  if (epi == 0) {
    const int e0 = bn * 128;
    const int g = e0 >> 10;
    const int h0 = (e0 & 1023) >> 6;  // tile covers heads h0, h0+1
    ushort* Ct = SMEM;                // 128 x 136 staging (aliases dbuf)
    __syncthreads();                  // full drain before LDS reuse

    if (g == 2) {
      // V: transposed staging T[col][row] -> uint2 writes (4 consecutive rows)
      for (int rt = 0; rt < 4; ++rt)
        for (int ct = 0; ct < 4; ++ct) {
          int col = wn + ct * 16 + lc;
          int r0 = wm + rt * 16 + quad * 4;
          uint2 pk = {pack2(acc[rt][ct][0], acc[rt][ct][1]),
                      pack2(acc[rt][ct][2], acc[rt][ct][3])};
          *(uint2*)&Ct[col * 136 + r0] = pk;
        }
    } else {
      // Q/K: rope + row-major staging
      const float qs = (g == 0) ? 0.125f * LOG2E : 1.0f;
      const float ang = powf(1e-4f, (float)lc * (1.0f / 15.0f));
      for (int rt = 0; rt < 4; ++rt)
        for (int r = 0; r < 4; ++r) {
          int row = wm + rt * 16 + quad * 4 + r;
          int srow = (bm * 128 + row) & 2047;
          float theta = (float)srow * ang;
          float sn, c;
          sincosf(theta, &sn, &c);
          float x1 = acc[rt][0][r], x2 = acc[rt][2][r];
          acc[rt][0][r] = x1 * c - x2 * sn;
          acc[rt][2][r] = x1 * sn + x2 * c;
          for (int ct = 0; ct < 4; ++ct)
            Ct[row * 136 + wn + ct * 16 + lc] = f2bf(acc[rt][ct][r] * qs);
        }
    }
    __syncthreads();

    if (g == 0) {
      for (int i = 0; i < 8; ++i) {
        int u = i * 256 + tid;
        int row = u >> 4, c8 = u & 15;
        int m = bm * 128 + row;
        int srow = m & 2047, b = m >> 11;
        uint4 vv = *(const uint4*)&Ct[row * 136 + c8 * 8];
        *(uint4*)&qb[(((long)(b * 16 + h0 + (c8 >> 3))) * 2048 + srow) * 64 +
                     (c8 & 7) * 8] = vv;
      }
    } else if (g == 1) {
      for (int i = 0; i < 8; ++i) {
        int u = i * 256 + tid;
        int head = u >> 10, off = u & 1023;
        int jrel = off >> 9, kc = (off >> 8) & 1, t = (off >> 6) & 3;
        int quadK = (off >> 4) & 3, lcA = off & 15;
        int srl = jrel * 64 + t * 16 + lcA;
        uint4 vv = *(const uint4*)&Ct[srl * 136 + head * 64 + kc * 32 + quadK * 8];
        int m = bm * 128 + srl;
        int srow = m & 2047, b = m >> 11;
        int bh = b * 16 + h0 + head;
        int chunk = (srow >> 6) * 8 + kc * 4 + t;
        *(uint4*)&kb[(long)bh * 131072 + chunk * 512 + (quadK * 16 + lcA) * 8] = vv;
      }
    } else {
      for (int i = 0; i < 8; ++i) {
        int u = i * 256 + tid;
        int head = u >> 10, off = u & 1023;
        int jrel = off >> 9, kcV = (off >> 8) & 1, mt = (off >> 6) & 3;
        int quadV = (off >> 4) & 3, lcA = off & 15;
        int srl = jrel * 64 + kcV * 32 + quadV * 8;
        int d = mt * 16 + lcA;
        uint4 vv = *(const uint4*)&Ct[(head * 64 + d) * 136 + srl];
        int m = bm * 128 + srl;
        int srow = m & 2047, b = m >> 11;
        int bh = b * 16 + h0 + head;
        int chunk = (srow >> 6) * 8 + kcV * 4 + mt;
        *(uint4*)&vb[(long)bh * 131072 + chunk * 512 + (quadV * 16 + lcA) * 8] = vv;
      }
    }
  } else {
    const int row0 = bm * 128 + wm;
    for (int rt = 0; rt < 4; ++rt)
      for (int r = 0; r < 4; ++r) {
        int m = row0 + rt * 16 + quad * 4 + r;
        float* drow = Cout + (long)m * 1024 + bn * 128 + wn;
        for (int ct = 0; ct < 4; ++ct)
          drow[ct * 16 + lc] = acc[rt][ct][r];
      }
  }
}

// ---------------------------------------------------------------- attention
// ONE WAVE PER BLOCK, 32 q-rows. Fragment-major coalesced K/V loads (r21),
// fixed-max softmax with bias dropped, 2x-unrolled A/B register ping-pong.
__global__ __launch_bounds__(64) void attn_kernel(
    const ushort* __restrict__ qb, const ushort* __restrict__ kb,
    const ushort* __restrict__ vt, ushort* __restrict__ out) {
  __shared__ __align__(16) ushort Psw2[2][32 * 64];
  const int lane = threadIdx.x;
  const int quad = lane >> 4, lc = lane & 15, l7 = lc & 7;
  const int bid = blockIdx.x;                   // 0..2047
  const int s = 63 - (bid >> 5);                // strip, big-work first
  const int bh = bid & 31;
  const int bidx = bh >> 4, h = bh & 15;
  const int qtbase = s * 32;

  bf16x8 qf[2][2];
  for (int kc = 0; kc < 2; ++kc)
    for (int q2 = 0; q2 < 2; ++q2)
      qf[kc][q2] = *(const bf16x8*)&qb[((long)bh * 2048 + qtbase + q2 * 16 + lc) * 64 +
                                       kc * 32 + quad * 8];

  f32x4 oacc[4][2] = {};
  float l_lane[2] = {0.0f, 0.0f};

  const ushort* K = kb + (long)bh * 131072;
  const ushort* Vt = vt + (long)bh * 131072;
  const int jmax = s >> 1;
  const int rowoff = (s & 1) * 32;
  const int lane8 = lane * 8;

#define LOADTILE(KF, VF, JT)                                                   \
  {                                                                            \
    const ushort* Kp_ = K + (JT) * 4096 + lane8;                               \
    const ushort* Vp_ = Vt + (JT) * 4096 + lane8;                              \
    for (int kc = 0; kc < 2; ++kc)                                             \
      for (int t = 0; t < 4; ++t) {                                            \
        KF[kc][t] = *(const bf16x8*)&Kp_[(kc * 4 + t) * 512];                  \
        VF[kc][t] = *(const bf16x8*)&Vp_[(kc * 4 + t) * 512];                  \
      }                                                                        \
  }

#define COMPUTE(KF, VF, J, PAR)                                                \
  {                                                                            \
    f32x4 sacc[4][2] = {};                                                     \
    for (int kc = 0; kc < 2; ++kc)                                             \
      for (int kt = 0; kt < 4; ++kt)                                           \
        for (int q2 = 0; q2 < 2; ++q2)                                         \
          sacc[kt][q2] = __builtin_amdgcn_mfma_f32_16x16x32_bf16(              \
              KF[kc][kt], qf[kc][q2], sacc[kt][q2], 0, 0, 0);                  \
    if ((J) == jmax) { /* causal partial tile */                               \
      for (int kt = 0; kt < 4; ++kt)                                           \
        for (int q2 = 0; q2 < 2; ++q2) {                                       \
          int rowrel = rowoff + q2 * 16 + lc;                                  \
          for (int r = 0; r < 4; ++r)                                          \
            if (kt * 16 + quad * 4 + r > rowrel) sacc[kt][q2][r] = -1.0e30f;   \
        }                                                                      \
    }                                                                          \
    ushort* Psw = Psw2[PAR];                                                   \
    for (int q2 = 0; q2 < 2; ++q2) {                                           \
      float p[4][4];                                                           \
      float rs = 0.0f;                                                         \
      for (int kt = 0; kt < 4; ++kt)                                           \
        for (int r = 0; r < 4; ++r) {                                          \
          p[kt][r] = fexp2(sacc[kt][q2][r]);                                   \
          rs += p[kt][r];                                                      \
        }                                                                      \
      l_lane[q2] += rs;                                                        \
      for (int kt = 0; kt < 4; ++kt) {                                         \
        uint2 pk = {pack2t(p[kt][0], p[kt][1]), pack2t(p[kt][2], p[kt][3])};   \
        *(uint2*)&Psw[(q2 * 16 + lc) * 64 +                                    \
                      (((kt * 2 + (quad >> 1)) ^ l7) << 3) +                   \
                      ((quad & 1) << 2)] = pk;                                 \
      }                                                                        \
    }                                                                          \
    CBAR(); /* compiler-only: P writes before P reads (HW DS in-order) */      \
    for (int kc = 0; kc < 2; ++kc) {                                           \
      bf16x8 pf[2];                                                            \
      for (int q2 = 0; q2 < 2; ++q2)                                           \
        pf[q2] = *(const bf16x8*)&Psw[(q2 * 16 + lc) * 64 +                    \
                                      (((kc * 4 + quad) ^ l7) << 3)];          \
      for (int mt = 0; mt < 4; ++mt)                                           \
        for (int q2 = 0; q2 < 2; ++q2)                                         \
          oacc[mt][q2] = __builtin_amdgcn_mfma_f32_16x16x32_bf16(              \
              VF[kc][mt], pf[q2], oacc[mt][q2], 0, 0, 0);                      \
    }                                                                          \
  }

  // 2x-unrolled software pipeline with A/B register ping-pong.
  bf16x8 kA[2][4], vA[2][4], kB[2][4], vB[2][4];
  LOADTILE(kA, vA, 0);
  int j = 0;
  while (true) {
    int jn = (j < jmax) ? j + 1 : j;
    LOADTILE(kB, vB, jn);
    COMPUTE(kA, vA, j, 0);
    if (j >= jmax) break;
    ++j;
    int jn2 = (j < jmax) ? j + 1 : j;
    LOADTILE(kA, vA, jn2);
    COMPUTE(kB, vB, j, 1);
    if (j >= jmax) break;
    ++j;
  }
#undef LOADTILE
#undef COMPUTE

  // epilogue: reduce l across quads, normalize, store via LDS
  float l_[2];
  for (int q2 = 0; q2 < 2; ++q2) {
    float rs = l_lane[q2];
    rs += __shfl_xor(rs, 16, 64);
    rs += __shfl_xor(rs, 32, 64);
    l_[q2] = rs;
  }
  ushort* Psw = Psw2[0];
  CBAR();
  for (int q2 = 0; q2 < 2; ++q2) {
    float linv = 1.0f / l_[q2];
    for (int mt = 0; mt < 4; ++mt) {
      uint2 pk = {pack2(oacc[mt][q2][0] * linv, oacc[mt][q2][1] * linv),
                  pack2(oacc[mt][q2][2] * linv, oacc[mt][q2][3] * linv)};
      *(uint2*)&Psw[(q2 * 16 + lc) * 64 + (((mt * 2 + (quad >> 1)) ^ l7) << 3) +
                    ((quad & 1) << 2)] = pk;
    }
  }
  CBAR();
  {
    int r2 = lane >> 1;
    long mrow = (long)bidx * 2048 + qtbase + r2;
    for (int c = 0; c < 4; ++c) {
      int c8 = (lane & 1) * 4 + c;
      uint4 vv = *(const uint4*)&Psw[r2 * 64 + ((c8 ^ (r2 & 7)) << 3)];
      *(uint4*)&out[mrow * 1024 + h * 64 + c8 * 8] = vv;
    }
  }
}

extern "C" void kernel_launch(void* const* d_in, const int* in_sizes, int n_in,
                              void* d_out, int out_size, void* d_ws, size_t ws_size,
                              hipStream_t stream) {
  const float* x = nullptr;     // 4194304 elems
  const float* Wqkv = nullptr;  // 3145728 elems
  const float* Wo = nullptr;    // 1048576 elems
  for (int i = 0; i < n_in; ++i) {
    if (in_sizes[i] == 4194304) x = (const float*)d_in[i];
    else if (in_sizes[i] == 3145728) Wqkv = (const float*)d_in[i];
    else if (in_sizes[i] == 1048576) Wo = (const float*)d_in[i];
  }
  float* out = (float*)d_out;  // [4096,1024] fp32 (16 MiB)

  // Workspace (32 MiB) timeline:
  //  [0,8)   qbuf (Q row-major)          -> later Wo bf16 (woh)
  //  [8,16)  kbuf (K fragment-major)
  //  [16,24) vbuf (V fragment-major)
  //  [24,32) scratch: Wqkv bf16 before/during gemm1 -> attn output (ao) after
  ushort* qbuf = (ushort*)d_ws;
  ushort* kbuf = qbuf + 4194304;
  ushort* vbuf = kbuf + 4194304;
  ushort* scr4 = vbuf + 4194304;
  ushort* wqkvh = scr4;                // Wqkv bf16 [24..30)
  ushort* ao   = scr4;                 // attn out (after gemm1 done with B)
  ushort* woh  = qbuf;                 // Wo bf16 (after attn done with Q)
  ushort* xh   = (ushort*)d_out;       // x_bf16 in d_out scratch

  conv_bf16_2<<<3584, 256, 0, stream>>>(x, xh, 524288, Wqkv, wqkvh, 393216);
  gemm_bt<<<768, 256, 0, stream>>>(xh, wqkvh, 24, qbuf, kbuf, vbuf, nullptr, 0);
  attn_kernel<<<2048, 64, 0, stream>>>(qbuf, kbuf, vbuf, ao);
  conv_bf16<<<512, 256, 0, stream>>>(Wo, woh, 131072);
  gemm_bt<<<256, 256, 0, stream>>>(ao, woh, 8, nullptr, nullptr, nullptr, out, 1);
}

// Round 8
// 185.722 us; speedup vs baseline: 1.0952x; 1.0952x over previous
//
#include <hip/hip_runtime.h>
#include <hip/hip_bf16.h>

// B=2, S=2048, D=1024, H=16, dk=64. INPUTS FP32, OUTPUT FP32. M = 4096 rows.
// ROUND 26 (= r25 resubmit; prior round was an infra failure, no data).
// SINGLE-BARRIER PIPELINED GEMM K-LOOP (3-buffer ring, stage-2-ahead, counted
// vmcnt). r24 eliminated bank conflicts (9.6M -> 164K) but regressed
// (64.9 -> 74.8us): 64 barriers/loop with 16 MFMA between pairs + 1-step
// prefetch window < load latency. Now:
//   step k: vmcnt(4); s_barrier; ds_read buf[k%3] + 16 MFMA; stage tile k+2
//           into buf[(k+2)%3]   (ONE barrier/step, 32 total)
// Race-free: buf[(k+2)%3] was last read in compute(k-1); all waves passed
// BAR_k only after completing those reads (MFMA reg deps force lgkm), and the
// stage is issued after BAR_k. vmcnt(4) retires exactly tile k's 4 loads;
// tiles k+1/k+2 stay in flight across the barrier (drain only at k=31).
// Loads get ~2 step-times to land. LDS 48KB -> still 3 blocks/CU.
// Fragment-major LDS (zero-conflict lane-linear ds_read_b128) kept from r24.

typedef __bf16 bf16x8 __attribute__((ext_vector_type(8)));
typedef float f32x4 __attribute__((ext_vector_type(4)));

#define LOG2E 1.4426950408889634f

__device__ __forceinline__ ushort f2bf(float f) {
  __hip_bfloat16 h = __float2bfloat16(f);
  return __builtin_bit_cast(ushort, h);
}

__device__ __forceinline__ uint pack2(float a, float b) {
  return (uint)f2bf(a) | ((uint)f2bf(b) << 16);
}

// truncating bf16x2 pack in one v_perm_b32
__device__ __forceinline__ uint pack2t(float a, float b) {
  return __builtin_amdgcn_perm(__builtin_bit_cast(uint, b),
                               __builtin_bit_cast(uint, a), 0x07060302u);
}

// single-instruction 2^x (quarter-rate trans pipe)
__device__ __forceinline__ float fexp2(float x) {
#if __has_builtin(__builtin_amdgcn_exp2f)
  return __builtin_amdgcn_exp2f(x);
#else
  float r;
  asm volatile("v_exp_f32 %0, %1\n\ts_nop 0" : "=v"(r) : "v"(x));
  return r;
#endif
}

#define CBAR() __asm__ __volatile__("" ::: "memory")

__device__ __forceinline__ void gl2lds16(const ushort* g, ushort* l) {
  __builtin_amdgcn_global_load_lds(
      (const __attribute__((address_space(1))) void*)g,
      (__attribute__((address_space(3))) void*)l, 16, 0, 0);
}

// ------------------------------------------------------- fp32 -> bf16 convs
__global__ __launch_bounds__(256) void conv_bf16(const float* __restrict__ src,
                                                 ushort* __restrict__ dst,
                                                 int n8) {
  int i = blockIdx.x * 256 + threadIdx.x;
  if (i >= n8) return;
  const float4* s = (const float4*)src + (long)i * 2;
  float4 a = s[0], b = s[1];
  uint4 pk = {pack2(a.x, a.y), pack2(a.z, a.w), pack2(b.x, b.y), pack2(b.z, b.w)};
  ((uint4*)dst)[i] = pk;
}

// two-segment conversion (x -> xh, Wqkv -> wqkvh) in one dispatch
__global__ __launch_bounds__(256) void conv_bf16_2(
    const float* __restrict__ s0, ushort* __restrict__ d0, int n0,
    const float* __restrict__ s1, ushort* __restrict__ d1, int n1) {
  int i = blockIdx.x * 256 + threadIdx.x;
  const float* src;
  ushort* dst;
  if (i < n0) {
    src = s0; dst = d0;
  } else {
    i -= n0;
    if (i >= n1) return;
    src = s1; dst = d1;
  }
  const float4* s = (const float4*)src + (long)i * 2;
  float4 a = s[0], b = s[1];
  uint4 pk = {pack2(a.x, a.y), pack2(a.z, a.w), pack2(b.x, b.y), pack2(b.z, b.w)};
  ((uint4*)dst)[i] = pk;
}

// ---------------------------------------------------------------- GEMM (NT)
// A [M x 1024] bf16 row-major, B [N x 1024] bf16 row-major (B^T GEMM).
// epi==0: QKV epilogue via LDS staging + coalesced uint4 stores (validated r22).
// epi==1: plain fp32 C row store.
__global__ __launch_bounds__(256) void gemm_bt(
    const ushort* __restrict__ A, const ushort* __restrict__ B, int nbn,
    ushort* __restrict__ qb, ushort* __restrict__ kb, ushort* __restrict__ vb,
    float* __restrict__ Cout, int epi) {
  // 3 ring buffers x (A 4096 | B 4096) ushorts = 48KB; epilogue Ct 128x136
  // (17408 ushorts) aliases the same LDS.
  __shared__ __align__(16) ushort SMEM[24576];
  const int tid = threadIdx.x;
  const int w = tid >> 6, lane = tid & 63, quad = lane >> 4, lc = lane & 15;
  const int bid = blockIdx.x;
  const int bm = bid / nbn, bn = bid % nbn;
  const int wm = (w & 1) * 64, wn = (w >> 1) * 64;

  f32x4 acc[4][4] = {};

  const ushort* Ag = A + (long)bm * 131072;
  const ushort* Bg = B + (long)bn * 131072;

  // fragment-major staging (validated r24): chunk c (0..7) of a 128x32 tile
  // holds rows (c>>2)*64 + (c&3)*16 + (lane&15), cols (lane>>4)*8..+7,
  // lane-contiguous 16B. Wave w stages chunks {w, w+4} of A and of B.
  const int aoff0 = (w * 16 + lc) * 1024 + quad * 8;  // chunk w   (rows 0..63)
  const int aoff1 = aoff0 + 65536;                    // chunk w+4 (rows 64..127)

#define STAGE(BUF, K0)                                                         \
  {                                                                            \
    gl2lds16(Ag + aoff0 + (K0), (BUF) + w * 512);                              \
    gl2lds16(Ag + aoff1 + (K0), (BUF) + (w + 4) * 512);                        \
    gl2lds16(Bg + aoff0 + (K0), (BUF) + 4096 + w * 512);                       \
    gl2lds16(Bg + aoff1 + (K0), (BUF) + 4096 + (w + 4) * 512);                 \
  }

  // prologue: tiles 0,1 into bufs 0,1 (8 loads in flight)
  STAGE(SMEM, 0);
  STAGE(SMEM + 8192, 32);

  int ci = 0;  // compute-buffer index = k % 3
  for (int k = 0; k < 32; ++k) {
    if (k < 31) {
      asm volatile("s_waitcnt vmcnt(4)" ::: "memory");  // tile k landed
    } else {
      asm volatile("s_waitcnt vmcnt(0)" ::: "memory");
    }
    __builtin_amdgcn_s_barrier();  // all waves' tile-k writes visible
    CBAR();
    {
      ushort* cur = SMEM + ci * 8192;
      const ushort* Ab = cur + (w & 1) * 2048 + lane * 8;
      const ushort* Bb = cur + 4096 + (w >> 1) * 2048 + lane * 8;
      bf16x8 af[4], bfr[4];
      for (int t = 0; t < 4; ++t) af[t] = *(const bf16x8*)&Ab[t * 512];
      for (int t = 0; t < 4; ++t) bfr[t] = *(const bf16x8*)&Bb[t * 512];
      for (int rt = 0; rt < 4; ++rt)
        for (int ct = 0; ct < 4; ++ct)
          acc[rt][ct] = __builtin_amdgcn_mfma_f32_16x16x32_bf16(
              af[rt], bfr[ct], acc[rt][ct], 0, 0, 0);
    }
    CBAR();
    if (k < 30) {  // stage tile k+2 into buf[(k+2)%3] (== (ci+2)%3)
      int si = (ci == 0) ? 2 : ci - 1;
      STAGE(SMEM + si * 8192, (k + 2) * 32);
    }
    ci = (ci == 2) ? 0 : ci + 1;
  }
#undef STAGE

  if (epi == 0) {
    const int e0 = bn * 128;
    const int g = e0 >> 10;
    const int h0 = (e0 & 1023) >> 6;  // tile covers heads h0, h0+1
    ushort* Ct = SMEM;                // 128 x 136 staging (aliases ring bufs)
    __syncthreads();                  // full drain before LDS reuse

    if (g == 2) {
      // V: transposed staging T[col][row] -> uint2 writes (4 consecutive rows)
      for (int rt = 0; rt < 4; ++rt)
        for (int ct = 0; ct < 4; ++ct) {
          int col = wn + ct * 16 + lc;
          int r0 = wm + rt * 16 + quad * 4;
          uint2 pk = {pack2(acc[rt][ct][0], acc[rt][ct][1]),
                      pack2(acc[rt][ct][2], acc[rt][ct][3])};
          *(uint2*)&Ct[col * 136 + r0] = pk;
        }
    } else {
      // Q/K: rope + row-major staging
      const float qs = (g == 0) ? 0.125f * LOG2E : 1.0f;
      const float ang = powf(1e-4f, (float)lc * (1.0f / 15.0f));
      for (int rt = 0; rt < 4; ++rt)
        for (int r = 0; r < 4; ++r) {
          int row = wm + rt * 16 + quad * 4 + r;
          int srow = (bm * 128 + row) & 2047;
          float theta = (float)srow * ang;
          float sn, c;
          sincosf(theta, &sn, &c);
          float x1 = acc[rt][0][r], x2 = acc[rt][2][r];
          acc[rt][0][r] = x1 * c - x2 * sn;
          acc[rt][2][r] = x1 * sn + x2 * c;
          for (int ct = 0; ct < 4; ++ct)
            Ct[row * 136 + wn + ct * 16 + lc] = f2bf(acc[rt][ct][r] * qs);
        }
    }
    __syncthreads();

    if (g == 0) {
      for (int i = 0; i < 8; ++i) {
        int u = i * 256 + tid;
        int row = u >> 4, c8 = u & 15;
        int m = bm * 128 + row;
        int srow = m & 2047, b = m >> 11;
        uint4 vv = *(const uint4*)&Ct[row * 136 + c8 * 8];
        *(uint4*)&qb[(((long)(b * 16 + h0 + (c8 >> 3))) * 2048 + srow) * 64 +
                     (c8 & 7) * 8] = vv;
      }
    } else if (g == 1) {
      for (int i = 0; i < 8; ++i) {
        int u = i * 256 + tid;
        int head = u >> 10, off = u & 1023;
        int jrel = off >> 9, kc = (off >> 8) & 1, t = (off >> 6) & 3;
        int quadK = (off >> 4) & 3, lcA = off & 15;
        int srl = jrel * 64 + t * 16 + lcA;
        uint4 vv = *(const uint4*)&Ct[srl * 136 + head * 64 + kc * 32 + quadK * 8];
        int m = bm * 128 + srl;
        int srow = m & 2047, b = m >> 11;
        int bh = b * 16 + h0 + head;
        int chunk = (srow >> 6) * 8 + kc * 4 + t;
        *(uint4*)&kb[(long)bh * 131072 + chunk * 512 + (quadK * 16 + lcA) * 8] = vv;
      }
    } else {
      for (int i = 0; i < 8; ++i) {
        int u = i * 256 + tid;
        int head = u >> 10, off = u & 1023;
        int jrel = off >> 9, kcV = (off >> 8) & 1, mt = (off >> 6) & 3;
        int quadV = (off >> 4) & 3, lcA = off & 15;
        int srl = jrel * 64 + kcV * 32 + quadV * 8;
        int d = mt * 16 + lcA;
        uint4 vv = *(const uint4*)&Ct[(head * 64 + d) * 136 + srl];
        int m = bm * 128 + srl;
        int srow = m & 2047, b = m >> 11;
        int bh = b * 16 + h0 + head;
        int chunk = (srow >> 6) * 8 + kcV * 4 + mt;
        *(uint4*)&vb[(long)bh * 131072 + chunk * 512 + (quadV * 16 + lcA) * 8] = vv;
      }
    }
  } else {
    const int row0 = bm * 128 + wm;
    for (int rt = 0; rt < 4; ++rt)
      for (int r = 0; r < 4; ++r) {
        int m = row0 + rt * 16 + quad * 4 + r;
        float* drow = Cout + (long)m * 1024 + bn * 128 + wn;
        for (int ct = 0; ct < 4; ++ct)
          drow[ct * 16 + lc] = acc[rt][ct][r];
      }
  }
}

// ---------------------------------------------------------------- attention
// ONE WAVE PER BLOCK, 32 q-rows. Fragment-major coalesced K/V loads (r21),
// fixed-max softmax with bias dropped, 2x-unrolled A/B register ping-pong.
__global__ __launch_bounds__(64) void attn_kernel(
    const ushort* __restrict__ qb, const ushort* __restrict__ kb,
    const ushort* __restrict__ vt, ushort* __restrict__ out) {
  __shared__ __align__(16) ushort Psw2[2][32 * 64];
  const int lane = threadIdx.x;
  const int quad = lane >> 4, lc = lane & 15, l7 = lc & 7;
  const int bid = blockIdx.x;                   // 0..2047
  const int s = 63 - (bid >> 5);                // strip, big-work first
  const int bh = bid & 31;
  const int bidx = bh >> 4, h = bh & 15;
  const int qtbase = s * 32;

  bf16x8 qf[2][2];
  for (int kc = 0; kc < 2; ++kc)
    for (int q2 = 0; q2 < 2; ++q2)
      qf[kc][q2] = *(const bf16x8*)&qb[((long)bh * 2048 + qtbase + q2 * 16 + lc) * 64 +
                                       kc * 32 + quad * 8];

  f32x4 oacc[4][2] = {};
  float l_lane[2] = {0.0f, 0.0f};

  const ushort* K = kb + (long)bh * 131072;
  const ushort* Vt = vt + (long)bh * 131072;
  const int jmax = s >> 1;
  const int rowoff = (s & 1) * 32;
  const int lane8 = lane * 8;

#define LOADTILE(KF, VF, JT)                                                   \
  {                                                                            \
    const ushort* Kp_ = K + (JT) * 4096 + lane8;                               \
    const ushort* Vp_ = Vt + (JT) * 4096 + lane8;                              \
    for (int kc = 0; kc < 2; ++kc)                                             \
      for (int t = 0; t < 4; ++t) {                                            \
        KF[kc][t] = *(const bf16x8*)&Kp_[(kc * 4 + t) * 512];                  \
        VF[kc][t] = *(const bf16x8*)&Vp_[(kc * 4 + t) * 512];                  \
      }                                                                        \
  }

#define COMPUTE(KF, VF, J, PAR)                                                \
  {                                                                            \
    f32x4 sacc[4][2] = {};                                                     \
    for (int kc = 0; kc < 2; ++kc)                                             \
      for (int kt = 0; kt < 4; ++kt)                                           \
        for (int q2 = 0; q2 < 2; ++q2)                                         \
          sacc[kt][q2] = __builtin_amdgcn_mfma_f32_16x16x32_bf16(              \
              KF[kc][kt], qf[kc][q2], sacc[kt][q2], 0, 0, 0);                  \
    if ((J) == jmax) { /* causal partial tile */                               \
      for (int kt = 0; kt < 4; ++kt)                                           \
        for (int q2 = 0; q2 < 2; ++q2) {                                       \
          int rowrel = rowoff + q2 * 16 + lc;                                  \
          for (int r = 0; r < 4; ++r)                                          \
            if (kt * 16 + quad * 4 + r > rowrel) sacc[kt][q2][r] = -1.0e30f;   \
        }                                                                      \
    }                                                                          \
    ushort* Psw = Psw2[PAR];                                                   \
    for (int q2 = 0; q2 < 2; ++q2) {                                           \
      float p[4][4];                                                           \
      float rs = 0.0f;                                                         \
      for (int kt = 0; kt < 4; ++kt)                                           \
        for (int r = 0; r < 4; ++r) {                                          \
          p[kt][r] = fexp2(sacc[kt][q2][r]);                                   \
          rs += p[kt][r];                                                      \
        }                                                                      \
      l_lane[q2] += rs;                                                        \
      for (int kt = 0; kt < 4; ++kt) {                                         \
        uint2 pk = {pack2t(p[kt][0], p[kt][1]), pack2t(p[kt][2], p[kt][3])};   \
        *(uint2*)&Psw[(q2 * 16 + lc) * 64 +                                    \
                      (((kt * 2 + (quad >> 1)) ^ l7) << 3) +                   \
                      ((quad & 1) << 2)] = pk;                                 \
      }                                                                        \
    }                                                                          \
    CBAR(); /* compiler-only: P writes before P reads (HW DS in-order) */      \
    for (int kc = 0; kc < 2; ++kc) {                                           \
      bf16x8 pf[2];                                                            \
      for (int q2 = 0; q2 < 2; ++q2)                                           \
        pf[q2] = *(const bf16x8*)&Psw[(q2 * 16 + lc) * 64 +                    \
                                      (((kc * 4 + quad) ^ l7) << 3)];          \
      for (int mt = 0; mt < 4; ++mt)                                           \
        for (int q2 = 0; q2 < 2; ++q2)                                         \
          oacc[mt][q2] = __builtin_amdgcn_mfma_f32_16x16x32_bf16(              \
              VF[kc][mt], pf[q2], oacc[mt][q2], 0, 0, 0);                      \
    }                                                                          \
  }

  // 2x-unrolled software pipeline with A/B register ping-pong.
  bf16x8 kA[2][4], vA[2][4], kB[2][4], vB[2][4];
  LOADTILE(kA, vA, 0);
  int j = 0;
  while (true) {
    int jn = (j < jmax) ? j + 1 : j;
    LOADTILE(kB, vB, jn);
    COMPUTE(kA, vA, j, 0);
    if (j >= jmax) break;
    ++j;
    int jn2 = (j < jmax) ? j + 1 : j;
    LOADTILE(kA, vA, jn2);
    COMPUTE(kB, vB, j, 1);
    if (j >= jmax) break;
    ++j;
  }
#undef LOADTILE
#undef COMPUTE

  // epilogue: reduce l across quads, normalize, store via LDS
  float l_[2];
  for (int q2 = 0; q2 < 2; ++q2) {
    float rs = l_lane[q2];
    rs += __shfl_xor(rs, 16, 64);
    rs += __shfl_xor(rs, 32, 64);
    l_[q2] = rs;
  }
  ushort* Psw = Psw2[0];
  CBAR();
  for (int q2 = 0; q2 < 2; ++q2) {
    float linv = 1.0f / l_[q2];
    for (int mt = 0; mt < 4; ++mt) {
      uint2 pk = {pack2(oacc[mt][q2][0] * linv, oacc[mt][q2][1] * linv),
                  pack2(oacc[mt][q2][2] * linv, oacc[mt][q2][3] * linv)};
      *(uint2*)&Psw[(q2 * 16 + lc) * 64 + (((mt * 2 + (quad >> 1)) ^ l7) << 3) +
                    ((quad & 1) << 2)] = pk;
    }
  }
  CBAR();
  {
    int r2 = lane >> 1;
    long mrow = (long)bidx * 2048 + qtbase + r2;
    for (int c = 0; c < 4; ++c) {
      int c8 = (lane & 1) * 4 + c;
      uint4 vv = *(const uint4*)&Psw[r2 * 64 + ((c8 ^ (r2 & 7)) << 3)];
      *(uint4*)&out[mrow * 1024 + h * 64 + c8 * 8] = vv;
    }
  }
}

extern "C" void kernel_launch(void* const* d_in, const int* in_sizes, int n_in,
                              void* d_out, int out_size, void* d_ws, size_t ws_size,
                              hipStream_t stream) {
  const float* x = nullptr;     // 4194304 elems
  const float* Wqkv = nullptr;  // 3145728 elems
  const float* Wo = nullptr;    // 1048576 elems
  for (int i = 0; i < n_in; ++i) {
    if (in_sizes[i] == 4194304) x = (const float*)d_in[i];
    else if (in_sizes[i] == 3145728) Wqkv = (const float*)d_in[i];
    else if (in_sizes[i] == 1048576) Wo = (const float*)d_in[i];
  }
  float* out = (float*)d_out;  // [4096,1024] fp32 (16 MiB)

  // Workspace (32 MiB) timeline:
  //  [0,8)   qbuf (Q row-major)          -> later Wo bf16 (woh)
  //  [8,16)  kbuf (K fragment-major)
  //  [16,24) vbuf (V fragment-major)
  //  [24,32) scratch: Wqkv bf16 before/during gemm1 -> attn output (ao) after
  ushort* qbuf = (ushort*)d_ws;
  ushort* kbuf = qbuf + 4194304;
  ushort* vbuf = kbuf + 4194304;
  ushort* scr4 = vbuf + 4194304;
  ushort* wqkvh = scr4;                // Wqkv bf16 [24..30)
  ushort* ao   = scr4;                 // attn out (after gemm1 done with B)
  ushort* woh  = qbuf;                 // Wo bf16 (after attn done with Q)
  ushort* xh   = (ushort*)d_out;       // x_bf16 in d_out scratch

  conv_bf16_2<<<3584, 256, 0, stream>>>(x, xh, 524288, Wqkv, wqkvh, 393216);
  gemm_bt<<<768, 256, 0, stream>>>(xh, wqkvh, 24, qbuf, kbuf, vbuf, nullptr, 0);
  attn_kernel<<<2048, 64, 0, stream>>>(qbuf, kbuf, vbuf, ao);
  conv_bf16<<<512, 256, 0, stream>>>(Wo, woh, 131072);
  gemm_bt<<<256, 256, 0, stream>>>(ao, woh, 8, nullptr, nullptr, nullptr, out, 1);
}